// Round 2
// baseline (162.278 us; speedup 1.0000x reference)
//
#include <hip/hip_runtime.h>
#include <math.h>

// ---------------------------------------------------------------------------
// YOLOv7 loss on MI355X — fused 2-launch version.
// Inputs (setup_inputs order):
//   d_in[0] p0: (16,255,80,80) f32
//   d_in[1] p1: (16,255,40,40) f32
//   d_in[2] p2: (16,255,20,20) f32
//   d_in[3] targets: (16,12,6) f32  [nb, cls, cx, cy, gw, gh]
//   d_in[4] image_size: (2,) f32
// Output: 4 f32 scalars [total, lbox*3.54, lobj*64.3, lcls*37.4]
//
// k_init  : zero the 16-word accumulator block in ws (ws is poisoned 0xAA).
// k_fused : blocks 0..143   -> per-(scale,b,a) objectness-plane softplus sum
//                              (float4 loads, contiguous planes)
//           blocks 144..146 -> generic on-device target assignment + per-match
//                              CIoU / cls-BCE / obj-correction (scale = bid-144)
//           last-done block -> finalize, write 4 outputs (device-scope
//                              done-counter + threadfence; acc re-read via
//                              atomicAdd(p,0) for cross-XCD visibility).
//
// lobj identity: mean(BCE(x,tobj)) = (sum softplus(x) - sum_matched x*clip(iou,0))/N
// ---------------------------------------------------------------------------

#define NT     192               // 16*12 targets
#define NOFF   5
#define NANCH  3
#define MAXC   (NANCH*NOFF*NT)   // 2880 combos per scale
#define THRESH 4.0f
#define NB     16
#define NCLS   80
#define NPLANE 144               // 3 scales * 16 batch * 3 anchors
#define NBLK   (NPLANE + 3)

__device__ __constant__ int   c_H[3]  = {80, 40, 20};
__device__ __constant__ int   c_W[3]  = {80, 40, 20};
__device__ __constant__ int   c_HW[3] = {6400, 1600, 400};
__device__ __constant__ float c_anch[18] = {10,13, 16,30, 33,23,
                                            30,61, 62,45, 59,119,
                                            116,90, 156,198, 373,326};
__device__ __constant__ float c_offs[10] = {0,0, 1,0, 0,1, -1,0, 0,-1};

// ws (float32 view) layout:
//   [0]      done counter (int)
//   [1..3]   n per scale (int)
//   [4..6]   sp_sum, [7..9] corr, [10..12] lbox_sum, [13..15] lcls_sum

__device__ __forceinline__ float sigmoidf(float x) {
    return 1.0f / (1.0f + __expf(-x));
}
__device__ __forceinline__ float softplusf(float x) {
    return fmaxf(x, 0.0f) + log1pf(expf(-fabsf(x)));
}

__global__ void k_init(float* __restrict__ ws) {
    if (threadIdx.x < 16) ws[threadIdx.x] = 0.0f;
}

__global__ void k_fused(const float* __restrict__ p0,
                        const float* __restrict__ p1,
                        const float* __restrict__ p2,
                        const float* __restrict__ targets,
                        const float* __restrict__ image_size,
                        float* __restrict__ ws,
                        float* __restrict__ out) {
    const int bid = blockIdx.x;
    const int tid = threadIdx.x;
    int* iws = (int*)ws;

    if (bid < NPLANE) {
        // ---- dense objectness softplus over one (scale,b,a) plane ----
        const int scale = bid / (NB * NANCH);
        const int rem   = bid % (NB * NANCH);
        const int b     = rem / NANCH;
        const int a     = rem % NANCH;
        const int HW    = c_HW[scale];
        const float* p  = (scale == 0) ? p0 : ((scale == 1) ? p1 : p2);
        // plane base offset is a multiple of 400 floats -> 16B aligned
        const float4* plane = (const float4*)(p + (size_t)b * 255 * HW
                                                + (size_t)(a * 85 + 4) * HW);
        const int n4 = HW >> 2;
        float s = 0.0f;
        for (int i = tid; i < n4; i += 256) {
            const float4 v = plane[i];
            s += softplusf(v.x) + softplusf(v.y) + softplusf(v.z) + softplusf(v.w);
        }
        for (int off = 32; off > 0; off >>= 1) s += __shfl_down(s, off, 64);
        __shared__ float sw[4];
        if ((tid & 63) == 0) sw[tid >> 6] = s;
        __syncthreads();
        if (tid == 0) atomicAdd(&ws[4 + scale], sw[0] + sw[1] + sw[2] + sw[3]);
    } else {
        // ---- target assignment + per-match losses for one scale ----
        const int scale = bid - NPLANE;
        __shared__ float s_t[NT * 6];
        __shared__ float s_isz[2];
        if (tid == 0) { s_isz[0] = image_size[0]; s_isz[1] = image_size[1]; }
        for (int k = tid; k < NT * 6; k += 256) s_t[k] = targets[k];
        __syncthreads();

        const int H = c_H[scale], W = c_W[scale];
        const int HW = c_HW[scale];
        const float gx_mul = (float)W / s_isz[1];
        const float gy_mul = (float)H / s_isz[0];
        const float* p = (scale == 0) ? p0 : ((scale == 1) ? p1 : p2);

        for (int k = tid; k < MAXC; k += 256) {
            const int a   = k / (NOFF * NT);
            const int rm  = k % (NOFF * NT);
            const int o   = rm / NT;
            const int t   = rm % NT;

            const float cx = s_t[t*6 + 2] * gx_mul;
            const float cy = s_t[t*6 + 3] * gy_mul;
            const float gw = s_t[t*6 + 4] * gx_mul;
            const float gh = s_t[t*6 + 5] * gy_mul;

            const float gxf = cx - c_offs[o*2 + 0];
            const float gyf = cy - c_offs[o*2 + 1];
            if (!(gxf >= 0.0f && gxf < (float)W && gyf >= 0.0f && gyf < (float)H))
                continue;

            const float aw = c_anch[(scale*3 + a)*2 + 0] * gx_mul;
            const float ah = c_anch[(scale*3 + a)*2 + 1] * gy_mul;
            const float rx = gw / aw, ry = gh / ah;
            const float mr = fmaxf(fmaxf(rx, 1.0f/rx), fmaxf(ry, 1.0f/ry));
            if (!(mr < THRESH)) continue;

            atomicAdd(&iws[1 + scale], 1);

            const int b   = (int)s_t[t*6 + 0];
            const int cls = (int)s_t[t*6 + 1];
            const int gi  = (int)gxf;
            const int gj  = (int)gyf;
            const float tbx = cx - (float)gi;
            const float tby = cy - (float)gj;

            const float* base = p + (size_t)b * 255 * HW + (size_t)(a * 85) * HW
                                  + (size_t)gj * W + gi;

            const float ps0 = base[0];
            const float ps1 = base[(size_t)HW];
            const float ps2 = base[2*(size_t)HW];
            const float ps3 = base[3*(size_t)HW];
            const float ps4 = base[4*(size_t)HW];

            const float px = sigmoidf(ps0) * 3.0f - 1.0f;
            const float py = sigmoidf(ps1) * 3.0f - 1.0f;
            float pw = sigmoidf(ps2) * 2.0f; pw = pw * pw * aw;
            float ph = sigmoidf(ps3) * 2.0f; ph = ph * ph * ah;

            const float eps = 1e-7f;
            const float b1x1 = px - pw*0.5f, b1x2 = px + pw*0.5f;
            const float b1y1 = py - ph*0.5f, b1y2 = py + ph*0.5f;
            const float b2x1 = tbx - gw*0.5f, b2x2 = tbx + gw*0.5f;
            const float b2y1 = tby - gh*0.5f, b2y2 = tby + gh*0.5f;
            const float iw = fmaxf(fminf(b1x2,b2x2) - fmaxf(b1x1,b2x1), 0.0f);
            const float ih = fmaxf(fminf(b1y2,b2y2) - fmaxf(b1y1,b2y1), 0.0f);
            const float inter = iw * ih;
            const float uni   = pw*ph + gw*gh - inter + eps;
            const float iou   = inter / uni;
            const float cwid  = fmaxf(b1x2,b2x2) - fminf(b1x1,b2x1);
            const float chgt  = fmaxf(b1y2,b2y2) - fminf(b1y1,b2y1);
            const float c2    = cwid*cwid + chgt*chgt + eps;
            const float dx    = b2x1 + b2x2 - b1x1 - b1x2;
            const float dy    = b2y1 + b2y2 - b1y1 - b1y2;
            const float rho2  = (dx*dx + dy*dy) * 0.25f;
            const float dv    = atanf(gw / (gh + eps)) - atanf(pw / (ph + eps));
            const float v     = 0.4052847345693511f * dv * dv;  // 4/pi^2
            const float alpha = v / (v - iou + (1.0f + eps));
            const float ciou  = iou - (rho2 / c2 + v * alpha);

            atomicAdd(&ws[10 + scale], 1.0f - ciou);
            atomicAdd(&ws[7  + scale], ps4 * fmaxf(ciou, 0.0f));

            float ls = 0.0f;
            for (int c = 0; c < NCLS; c++) {
                const float x  = base[(size_t)(5 + c) * HW];
                const float tv = (c == cls - 1) ? 1.0f : 0.0f;
                ls += fmaxf(x, 0.0f) - x * tv + log1pf(expf(-fabsf(x)));
            }
            atomicAdd(&ws[13 + scale], ls);
        }
    }

    // ---- completion: last block finalizes ----
    __syncthreads();
    if (tid == 0) {
        __threadfence();                       // make my atomics visible
        const int done = atomicAdd(&iws[0], 1);
        if (done == NBLK - 1) {
            // device-scope coherent re-reads
            float a[16];
            #pragma unroll
            for (int i = 4; i < 16; i++) a[i] = atomicAdd(&ws[i], 0.0f);
            int n[3];
            #pragma unroll
            for (int i = 0; i < 3; i++) n[i] = atomicAdd(&iws[1 + i], 0);

            const float bal[3] = {4.0f, 1.0f, 0.4f};
            float lobj = 0.0f, lbox = 0.0f, lcls = 0.0f;
            #pragma unroll
            for (int i = 0; i < 3; i++) {
                const float cnt = (float)(NB * NANCH * c_HW[i]);
                lobj += (a[4 + i] - a[7 + i]) / cnt * bal[i];
                if (n[i] > 0) {
                    lbox += a[10 + i] / (float)n[i];
                    lcls += a[13 + i] / ((float)n[i] * (float)NCLS);
                }
            }
            lbox *= 3.54f;
            lobj *= 64.3f;
            lcls *= 37.4f;
            out[0] = lbox + lobj + lcls;
            out[1] = lbox;
            out[2] = lobj;
            out[3] = lcls;
        }
    }
}

extern "C" void kernel_launch(void* const* d_in, const int* in_sizes, int n_in,
                              void* d_out, int out_size, void* d_ws, size_t ws_size,
                              hipStream_t stream) {
    const float* p0  = (const float*)d_in[0];
    const float* p1  = (const float*)d_in[1];
    const float* p2  = (const float*)d_in[2];
    const float* tgt = (const float*)d_in[3];
    const float* isz = (const float*)d_in[4];
    float* out = (float*)d_out;
    float* ws  = (float*)d_ws;

    k_init<<<1, 64, 0, stream>>>(ws);
    k_fused<<<NBLK, 256, 0, stream>>>(p0, p1, p2, tgt, isz, ws, out);
}

// Round 3
// 158.635 us; speedup vs baseline: 1.0230x; 1.0230x over previous
//
#include <hip/hip_runtime.h>
#include <math.h>

// ---------------------------------------------------------------------------
// YOLOv7 loss on MI355X — single-launch version.
// Inputs (setup_inputs order):
//   d_in[0] p0: (16,255,80,80) f32
//   d_in[1] p1: (16,255,40,40) f32
//   d_in[2] p2: (16,255,20,20) f32
//   d_in[3] targets: (16,12,6) f32  [nb, cls, cx, cy, gw, gh]
//   d_in[4] image_size: (2,) f32
// Output: 4 f32 scalars [total, lbox*3.54, lobj*64.3, lcls*37.4]
//
// One kernel, 147 blocks:
//   blocks 0..143  : per-(scale,b,a) objectness-plane softplus partial sum
//                    (float4 loads, fast __expf/__logf softplus)
//   blocks 144..146: generic on-device target assignment + per-match
//                    CIoU / cls-BCE / obj-correction partials (scale = bid-144)
//   block 146      : finalizer — spins on per-block magic flags (device-scope
//                    atomicOr reads; poison 0xAA != MAGIC so NO init kernel is
//                    needed), gathers partials, writes the 4 outputs.
//
// All cross-block values are written with device-scope atomicExch and read
// with atomicAdd(p,0) — coherent across XCDs. __threadfence() orders each
// block's partial writes before its flag write.
//
// lobj identity: mean(BCE(x,tobj)) = (sum softplus(x) - sum_matched x*clip(iou,0))/N
// ---------------------------------------------------------------------------

#define NT     192               // 16*12 targets
#define NOFF   5
#define NANCH  3
#define MAXC   (NANCH*NOFF*NT)   // 2880 combos per scale
#define THRESH 4.0f
#define NB     16
#define NCLS   80
#define NPLANE 144               // 3 scales * 16 batch * 3 anchors
#define NBLK   (NPLANE + 3)
#define MAGIC  0x5EED0001
// ws word layout
#define WS_FLAG   0              // [0..146] int flags
#define WS_DENSE  160            // [160..303] float: per-plane softplus partial
#define WS_ASSIGN 320            // [320+s*4 + {n,corr,lbox,lcls}]

__device__ __constant__ int   c_H[3]  = {80, 40, 20};
__device__ __constant__ int   c_W[3]  = {80, 40, 20};
__device__ __constant__ int   c_HW[3] = {6400, 1600, 400};
__device__ __constant__ float c_anch[18] = {10,13, 16,30, 33,23,
                                            30,61, 62,45, 59,119,
                                            116,90, 156,198, 373,326};
__device__ __constant__ float c_offs[10] = {0,0, 1,0, 0,1, -1,0, 0,-1};

__device__ __forceinline__ float sigmoidf(float x) {
    return 1.0f / (1.0f + __expf(-x));
}
__device__ __forceinline__ float softplusf(float x) {
    // fmax(x,0) + log1p(exp(-|x|)) with HW exp2/log2 — |err| ~1e-6 rel
    return fmaxf(x, 0.0f) + __logf(1.0f + __expf(-fabsf(x)));
}

__global__ void __launch_bounds__(256)
k_fused(const float* __restrict__ p0,
        const float* __restrict__ p1,
        const float* __restrict__ p2,
        const float* __restrict__ targets,
        const float* __restrict__ image_size,
        float* __restrict__ ws,
        float* __restrict__ out) {
    const int bid = blockIdx.x;
    const int tid = threadIdx.x;
    int* iws = (int*)ws;

    __shared__ float s_red[8];        // generic reduction scratch
    __shared__ float s_t[NT * 6];     // targets (assign blocks)
    __shared__ float s_isz[2];
    __shared__ float s_sp[3];         // finalizer per-scale sp sums

    if (tid < 8) s_red[tid] = 0.0f;
    if (tid < 3) s_sp[tid] = 0.0f;

    if (bid < NPLANE) {
        // ---- dense objectness softplus over one (scale,b,a) plane ----
        const int scale = bid / (NB * NANCH);
        const int rem   = bid % (NB * NANCH);
        const int b     = rem / NANCH;
        const int a     = rem % NANCH;
        const int HW    = c_HW[scale];
        const float* p  = (scale == 0) ? p0 : ((scale == 1) ? p1 : p2);
        const float4* plane = (const float4*)(p + (size_t)b * 255 * HW
                                                + (size_t)(a * 85 + 4) * HW);
        const int n4 = HW >> 2;
        float s = 0.0f;
        for (int i = tid; i < n4; i += 256) {
            const float4 v = plane[i];
            s += softplusf(v.x) + softplusf(v.y) + softplusf(v.z) + softplusf(v.w);
        }
        for (int off = 32; off > 0; off >>= 1) s += __shfl_down(s, off, 64);
        if ((tid & 63) == 0) s_red[tid >> 6] = s;
        __syncthreads();
        if (tid == 0) {
            const float part = s_red[0] + s_red[1] + s_red[2] + s_red[3];
            atomicExch(&ws[WS_DENSE + bid], part);
            __threadfence();
            atomicExch(&iws[WS_FLAG + bid], MAGIC);
        }
    } else {
        // ---- target assignment + per-match losses for one scale ----
        const int scale = bid - NPLANE;
        if (tid == 0) { s_isz[0] = image_size[0]; s_isz[1] = image_size[1]; }
        for (int k = tid; k < NT * 6; k += 256) s_t[k] = targets[k];
        __syncthreads();

        const int H = c_H[scale], W = c_W[scale];
        const int HW = c_HW[scale];
        const float gx_mul = (float)W / s_isz[1];
        const float gy_mul = (float)H / s_isz[0];
        const float* p = (scale == 0) ? p0 : ((scale == 1) ? p1 : p2);

        int   n_loc = 0;
        float corr_loc = 0.0f, lbox_loc = 0.0f, lcls_loc = 0.0f;

        for (int k = tid; k < MAXC; k += 256) {
            const int a   = k / (NOFF * NT);
            const int rm  = k % (NOFF * NT);
            const int o   = rm / NT;
            const int t   = rm % NT;

            const float cx = s_t[t*6 + 2] * gx_mul;
            const float cy = s_t[t*6 + 3] * gy_mul;
            const float gw = s_t[t*6 + 4] * gx_mul;
            const float gh = s_t[t*6 + 5] * gy_mul;

            const float gxf = cx - c_offs[o*2 + 0];
            const float gyf = cy - c_offs[o*2 + 1];
            if (!(gxf >= 0.0f && gxf < (float)W && gyf >= 0.0f && gyf < (float)H))
                continue;

            const float aw = c_anch[(scale*3 + a)*2 + 0] * gx_mul;
            const float ah = c_anch[(scale*3 + a)*2 + 1] * gy_mul;
            const float rx = gw / aw, ry = gh / ah;
            const float mr = fmaxf(fmaxf(rx, 1.0f/rx), fmaxf(ry, 1.0f/ry));
            if (!(mr < THRESH)) continue;

            n_loc++;

            const int b   = (int)s_t[t*6 + 0];
            const int cls = (int)s_t[t*6 + 1];
            const int gi  = (int)gxf;
            const int gj  = (int)gyf;
            const float tbx = cx - (float)gi;
            const float tby = cy - (float)gj;

            const float* base = p + (size_t)b * 255 * HW + (size_t)(a * 85) * HW
                                  + (size_t)gj * W + gi;

            const float ps0 = base[0];
            const float ps1 = base[(size_t)HW];
            const float ps2 = base[2*(size_t)HW];
            const float ps3 = base[3*(size_t)HW];
            const float ps4 = base[4*(size_t)HW];

            const float px = sigmoidf(ps0) * 3.0f - 1.0f;
            const float py = sigmoidf(ps1) * 3.0f - 1.0f;
            float pw = sigmoidf(ps2) * 2.0f; pw = pw * pw * aw;
            float ph = sigmoidf(ps3) * 2.0f; ph = ph * ph * ah;

            const float eps = 1e-7f;
            const float b1x1 = px - pw*0.5f, b1x2 = px + pw*0.5f;
            const float b1y1 = py - ph*0.5f, b1y2 = py + ph*0.5f;
            const float b2x1 = tbx - gw*0.5f, b2x2 = tbx + gw*0.5f;
            const float b2y1 = tby - gh*0.5f, b2y2 = tby + gh*0.5f;
            const float iw = fmaxf(fminf(b1x2,b2x2) - fmaxf(b1x1,b2x1), 0.0f);
            const float ih = fmaxf(fminf(b1y2,b2y2) - fmaxf(b1y1,b2y1), 0.0f);
            const float inter = iw * ih;
            const float uni   = pw*ph + gw*gh - inter + eps;
            const float iou   = inter / uni;
            const float cwid  = fmaxf(b1x2,b2x2) - fminf(b1x1,b2x1);
            const float chgt  = fmaxf(b1y2,b2y2) - fminf(b1y1,b2y1);
            const float c2    = cwid*cwid + chgt*chgt + eps;
            const float dx    = b2x1 + b2x2 - b1x1 - b1x2;
            const float dy    = b2y1 + b2y2 - b1y1 - b1y2;
            const float rho2  = (dx*dx + dy*dy) * 0.25f;
            const float dv    = atanf(gw / (gh + eps)) - atanf(pw / (ph + eps));
            const float v     = 0.4052847345693511f * dv * dv;  // 4/pi^2
            const float alpha = v / (v - iou + (1.0f + eps));
            const float ciou  = iou - (rho2 / c2 + v * alpha);

            lbox_loc += 1.0f - ciou;
            corr_loc += ps4 * fmaxf(ciou, 0.0f);

            float ls = 0.0f;
            for (int c = 0; c < NCLS; c++) {
                const float x  = base[(size_t)(5 + c) * HW];
                const float tv = (c == cls - 1) ? 1.0f : 0.0f;
                ls += fmaxf(x, 0.0f) - x * tv + __logf(1.0f + __expf(-fabsf(x)));
            }
            lcls_loc += ls;
        }

        // block reduction of the 4 partials via wave shuffles + LDS
        float nf = (float)n_loc;
        for (int off = 32; off > 0; off >>= 1) {
            nf       += __shfl_down(nf,       off, 64);
            corr_loc += __shfl_down(corr_loc, off, 64);
            lbox_loc += __shfl_down(lbox_loc, off, 64);
            lcls_loc += __shfl_down(lcls_loc, off, 64);
        }
        __shared__ float s_a[4][4];
        if ((tid & 63) == 0) {
            const int w = tid >> 6;
            s_a[w][0] = nf; s_a[w][1] = corr_loc;
            s_a[w][2] = lbox_loc; s_a[w][3] = lcls_loc;
        }
        __syncthreads();
        if (tid == 0) {
            const float n_s    = s_a[0][0]+s_a[1][0]+s_a[2][0]+s_a[3][0];
            const float corr_s = s_a[0][1]+s_a[1][1]+s_a[2][1]+s_a[3][1];
            const float lbox_s = s_a[0][2]+s_a[1][2]+s_a[2][2]+s_a[3][2];
            const float lcls_s = s_a[0][3]+s_a[1][3]+s_a[2][3]+s_a[3][3];
            const int basei = WS_ASSIGN + scale * 4;
            atomicExch(&iws[basei + 0], (int)(n_s + 0.5f));
            atomicExch(&ws [basei + 1], corr_s);
            atomicExch(&ws [basei + 2], lbox_s);
            atomicExch(&ws [basei + 3], lcls_s);
            __threadfence();
            atomicExch(&iws[WS_FLAG + bid], MAGIC);
        }
    }

    // ---- finalizer: block NBLK-1 waits for all flags, then reduces ----
    if (bid == NBLK - 1) {
        __syncthreads();
        if (tid < NBLK) {
            while (atomicOr(&iws[WS_FLAG + tid], 0) != MAGIC) {
                __builtin_amdgcn_s_sleep(1);
            }
        }
        __syncthreads();
        // gather dense partials -> per-scale LDS sums
        if (tid < NPLANE) {
            const float v = atomicAdd(&ws[WS_DENSE + tid], 0.0f);
            atomicAdd(&s_sp[tid / (NB * NANCH)], v);
        }
        __syncthreads();
        if (tid == 0) {
            const float bal[3] = {4.0f, 1.0f, 0.4f};
            float lobj = 0.0f, lbox = 0.0f, lcls = 0.0f;
            #pragma unroll
            for (int i = 0; i < 3; i++) {
                const int basei = WS_ASSIGN + i * 4;
                const int   n    = atomicAdd(&iws[basei + 0], 0);
                const float corr = atomicAdd(&ws [basei + 1], 0.0f);
                const float lbx  = atomicAdd(&ws [basei + 2], 0.0f);
                const float lcl  = atomicAdd(&ws [basei + 3], 0.0f);
                const float cnt  = (float)(NB * NANCH * c_HW[i]);
                lobj += (s_sp[i] - corr) / cnt * bal[i];
                if (n > 0) {
                    lbox += lbx / (float)n;
                    lcls += lcl / ((float)n * (float)NCLS);
                }
            }
            lbox *= 3.54f;
            lobj *= 64.3f;
            lcls *= 37.4f;
            out[0] = lbox + lobj + lcls;
            out[1] = lbox;
            out[2] = lobj;
            out[3] = lcls;
        }
    }
}

extern "C" void kernel_launch(void* const* d_in, const int* in_sizes, int n_in,
                              void* d_out, int out_size, void* d_ws, size_t ws_size,
                              hipStream_t stream) {
    const float* p0  = (const float*)d_in[0];
    const float* p1  = (const float*)d_in[1];
    const float* p2  = (const float*)d_in[2];
    const float* tgt = (const float*)d_in[3];
    const float* isz = (const float*)d_in[4];
    float* out = (float*)d_out;
    float* ws  = (float*)d_ws;

    k_fused<<<NBLK, 256, 0, stream>>>(p0, p1, p2, tgt, isz, ws, out);
}